// Round 1
// baseline (976.604 us; speedup 1.0000x reference)
//
#include <hip/hip_runtime.h>
#include <stdint.h>
#include <stddef.h>

// ---------- types ----------
typedef __attribute__((ext_vector_type(8))) short bf16x8;  // 8 bf16 (4 VGPRs)
typedef __attribute__((ext_vector_type(4))) short bf16x4;
typedef __attribute__((ext_vector_type(4))) float f32x4;

typedef const __attribute__((address_space(1))) uint32_t gas_u32;
typedef __attribute__((address_space(3))) uint32_t las_u32;

__device__ __forceinline__ short f2bf(float f) {
  union { float f; uint32_t u; } c; c.f = f;
  uint32_t u = c.u;
  u += 0x7fffu + ((u >> 16) & 1u);   // RNE
  return (short)(u >> 16);
}

// ---------- fp32 -> bf16 convert ----------
__global__ void k_cvt(const float* __restrict__ src, short* __restrict__ dst, int n) {
  int i = (blockIdx.x * 256 + threadIdx.x) * 4;
  if (i + 4 <= n) {
    float4 v = *(const float4*)(src + i);
    bf16x4 o = { f2bf(v.x), f2bf(v.y), f2bf(v.z), f2bf(v.w) };
    *(bf16x4*)(dst + i) = o;
  } else {
    for (; i < n; ++i) dst[i] = f2bf(src[i]);
  }
}

// gather rows [row0, row0+rpb) of each batch's (93,2048) context into packed (8*rpb,2048) bf16
__global__ void k_cvt_ctx(const float* __restrict__ ctx, short* __restrict__ dst,
                          int rpb, int row0) {
  long total = 8L * rpb * 2048;
  long i = ((long)blockIdx.x * 256 + threadIdx.x) * 4;
  if (i >= total) return;
  int c = (int)(i & 2047);
  long rs = i >> 11;
  int b = (int)(rs / rpb);
  int s = (int)(rs - (long)b * rpb);
  const float* sp = ctx + ((long)(b * 93 + row0 + s) * 2048 + c);
  float4 v = *(const float4*)sp;
  bf16x4 o = { f2bf(v.x), f2bf(v.y), f2bf(v.z), f2bf(v.w) };
  *(bf16x4*)(dst + i) = o;
}

// ---------- GEMM: C[M,N] = A[M,K] * B[N,K]^T  (both row-major, bf16, fp32 acc) ----------
// MODE 0: store bf16 with head permute: out[((b*20+h)*SPB + s)*64 + d], b=m/SPB, s=m%SPB, h=n>>6, d=n&63
// MODE 1: store fp32 row-major + bias[n]
template <int MODE>
__global__ __launch_bounds__(256)
void k_gemm(const short* __restrict__ A, const short* __restrict__ Bm,
            void* __restrict__ out, const float* __restrict__ bias,
            int Mreal, int N, int K, int SPB) {
  __shared__ __align__(16) short As[128 * 32];
  __shared__ __align__(16) short Bs[128 * 32];
  const int t = threadIdx.x;
  const int lane = t & 63, wave = t >> 6;
  const int wm = (wave >> 1) * 64, wn = (wave & 1) * 64;
  const int m0 = blockIdx.y * 128, n0 = blockIdx.x * 128;
  const int q4 = lane >> 4, r16 = lane & 15;

  f32x4 zero = {0.f, 0.f, 0.f, 0.f};
  f32x4 acc[4][4];
#pragma unroll
  for (int i = 0; i < 4; ++i)
#pragma unroll
    for (int j = 0; j < 4; ++j) acc[i][j] = zero;

  // staging: 512 16B chunks per tile over 256 threads (2 each); LDS dest is
  // lane-contiguous (global_load_lds constraint: wave-uniform base + lane*16)
  const int c0 = t, c1 = t + 256;
  const int ar0 = c0 >> 2, ao0 = (c0 & 3) * 8;
  const int ar1 = c1 >> 2, ao1 = (c1 & 3) * 8;
  int gm0 = m0 + ar0; if (gm0 >= Mreal) gm0 = Mreal - 1;
  int gm1 = m0 + ar1; if (gm1 >= Mreal) gm1 = Mreal - 1;
  const short* ga0 = A + (size_t)gm0 * K + ao0;
  const short* ga1 = A + (size_t)gm1 * K + ao1;
  const short* gb0 = Bm + (size_t)(n0 + ar0) * K + ao0;
  const short* gb1 = Bm + (size_t)(n0 + ar1) * K + ao1;

  for (int k0 = 0; k0 < K; k0 += 32) {
    __builtin_amdgcn_global_load_lds((gas_u32*)(ga0 + k0), (las_u32*)(As + c0 * 8), 16, 0, 0);
    __builtin_amdgcn_global_load_lds((gas_u32*)(ga1 + k0), (las_u32*)(As + c1 * 8), 16, 0, 0);
    __builtin_amdgcn_global_load_lds((gas_u32*)(gb0 + k0), (las_u32*)(Bs + c0 * 8), 16, 0, 0);
    __builtin_amdgcn_global_load_lds((gas_u32*)(gb1 + k0), (las_u32*)(Bs + c1 * 8), 16, 0, 0);
    __syncthreads();

    bf16x8 af[4], bf[4];
#pragma unroll
    for (int i = 0; i < 4; ++i)
      af[i] = *(const bf16x8*)(As + (wm + i * 16 + r16) * 32 + q4 * 8);
#pragma unroll
    for (int j = 0; j < 4; ++j)
      bf[j] = *(const bf16x8*)(Bs + (wn + j * 16 + r16) * 32 + q4 * 8);
#pragma unroll
    for (int i = 0; i < 4; ++i)
#pragma unroll
      for (int j = 0; j < 4; ++j)
        acc[i][j] = __builtin_amdgcn_mfma_f32_16x16x32_bf16(af[i], bf[j], acc[i][j], 0, 0, 0);
    __syncthreads();
  }

  // D layout (verified): row = q4*4 + reg, col = r16 within each 16x16 tile
  if (MODE == 0) {
    short* O = (short*)out;
#pragma unroll
    for (int i = 0; i < 4; ++i) {
#pragma unroll
      for (int rr = 0; rr < 4; ++rr) {
        int m = m0 + wm + i * 16 + q4 * 4 + rr;
        if (m < Mreal) {
          int bb, ss;
          if (SPB == 4096) { bb = m >> 12; ss = m & 4095; }
          else             { bb = m / SPB; ss = m - bb * SPB; }
#pragma unroll
          for (int j = 0; j < 4; ++j) {
            int n = n0 + wn + j * 16 + r16;
            int h = n >> 6, d = n & 63;
            O[(((size_t)(bb * 20 + h)) * SPB + ss) * 64 + d] = f2bf(acc[i][j][rr]);
          }
        }
      }
    }
  } else {
    float* O = (float*)out;
#pragma unroll
    for (int i = 0; i < 4; ++i) {
#pragma unroll
      for (int rr = 0; rr < 4; ++rr) {
        int m = m0 + wm + i * 16 + q4 * 4 + rr;
        if (m < Mreal) {
#pragma unroll
          for (int j = 0; j < 4; ++j) {
            int n = n0 + wn + j * 16 + r16;
            O[(size_t)m * N + n] = acc[i][j][rr] + bias[n];
          }
        }
      }
    }
  }
}

// ---------- fused dual attention: out = softmax(QKt^T/8)Vt + scale*softmax(QKi^T/8)Vi ----------
// Q,K,V in (b,h,s,64) bf16. Keys padded: rows 0..76 txt, 77..79 zero (masked), 80..95 img.
__global__ __launch_bounds__(256)
void k_attn(const short* __restrict__ qb, const short* __restrict__ kb,
            const short* __restrict__ vb, const short* __restrict__ kib,
            const short* __restrict__ vib, const float* __restrict__ scale_p,
            short* __restrict__ out) {
  constexpr int KS = 72;    // Ks row stride (shorts): 144B -> 2-way bank alias (free)
  constexpr int PS = 104;   // Vt/P row stride: 208B -> 2-way alias (free), 16B aligned
  __shared__ __align__(16) short Ks[96 * KS];
  __shared__ __align__(16) short Vt[64 * PS];      // transposed: Vt[d][key]
  __shared__ __align__(16) short Pp[4][16 * PS];   // per-wave P (A-layout staging)
  const int t = threadIdx.x, lane = t & 63, wave = t >> 6;
  const int q4 = lane >> 4, r16 = lane & 15;
  const int b = blockIdx.z, h = blockIdx.y, qt = blockIdx.x;
  const int bh = b * 20 + h;
  const short* kt = kb + (size_t)bh * 77 * 64;
  const short* vt = vb + (size_t)bh * 77 * 64;
  const short* ki = kib + (size_t)bh * 16 * 64;
  const short* vi = vib + (size_t)bh * 16 * 64;

  // stage K rows (16B chunks)
  for (int c = t; c < 96 * 8; c += 256) {
    int row = c >> 3, o = (c & 7) * 8;
    uint4 val = {0u, 0u, 0u, 0u};
    if (row < 77)       val = *(const uint4*)(kt + row * 64 + o);
    else if (row >= 80) val = *(const uint4*)(ki + (row - 80) * 64 + o);
    *(uint4*)(Ks + row * KS + o) = val;
  }
  // stage V transposed
  for (int i = t; i < 96 * 64; i += 256) {
    int key = i >> 6, d = i & 63;
    short v = 0;
    if (key < 77)       v = vt[key * 64 + d];
    else if (key >= 80) v = vi[(key - 80) * 64 + d];
    Vt[d * PS + key] = v;
  }
  __syncthreads();

  // per-wave: 16 q rows
  const int s0 = qt * 64 + wave * 16;
  const short* qp = qb + ((size_t)bh * 4096 + s0) * 64;
  bf16x8 qf[2];
#pragma unroll
  for (int kc = 0; kc < 2; ++kc)
    qf[kc] = *(const bf16x8*)(qp + r16 * 64 + kc * 32 + q4 * 8);

  f32x4 zero = {0.f, 0.f, 0.f, 0.f};
  f32x4 lg[6];  // logits tiles: 0..4 txt(80 padded), 5 img(16)
#pragma unroll
  for (int nt = 0; nt < 6; ++nt) {
    lg[nt] = zero;
#pragma unroll
    for (int kc = 0; kc < 2; ++kc) {
      bf16x8 kf = *(const bf16x8*)(Ks + (nt * 16 + r16) * KS + kc * 32 + q4 * 8);
      lg[nt] = __builtin_amdgcn_mfma_f32_16x16x32_bf16(qf[kc], kf, lg[nt], 0, 0, 0);
    }
  }

  const float sm = 0.125f;  // 1/sqrt(64)
  const float scl = scale_p[0];
#pragma unroll
  for (int nt = 0; nt < 6; ++nt)
#pragma unroll
    for (int rr = 0; rr < 4; ++rr) lg[nt][rr] *= sm;
  if (r16 >= 13) {  // txt tile 4: keys 64+r16 >= 77 are padding
#pragma unroll
    for (int rr = 0; rr < 4; ++rr) lg[4][rr] = -1e30f;
  }

  // two independent softmaxes; row rr lives in the 16 lanes of this quad at reg rr
#pragma unroll
  for (int rr = 0; rr < 4; ++rr) {
    float mx = -1e30f;
#pragma unroll
    for (int nt = 0; nt < 5; ++nt) mx = fmaxf(mx, lg[nt][rr]);
#pragma unroll
    for (int o = 1; o < 16; o <<= 1) mx = fmaxf(mx, __shfl_xor(mx, o, 64));
    float s = 0.f;
#pragma unroll
    for (int nt = 0; nt < 5; ++nt) {
      float p = __expf(lg[nt][rr] - mx);
      lg[nt][rr] = p; s += p;
    }
#pragma unroll
    for (int o = 1; o < 16; o <<= 1) s += __shfl_xor(s, o, 64);
    float inv = 1.f / s;
#pragma unroll
    for (int nt = 0; nt < 5; ++nt) lg[nt][rr] *= inv;

    float mi = lg[5][rr];
#pragma unroll
    for (int o = 1; o < 16; o <<= 1) mi = fmaxf(mi, __shfl_xor(mi, o, 64));
    float pi = __expf(lg[5][rr] - mi);
    float si = pi;
#pragma unroll
    for (int o = 1; o < 16; o <<= 1) si += __shfl_xor(si, o, 64);
    lg[5][rr] = pi * (scl / si);   // fold 'scale' into img probs
  }

  // C-layout -> A-layout via LDS round trip (wave-private, no barrier needed)
  short* pw = &Pp[wave][0];
#pragma unroll
  for (int nt = 0; nt < 6; ++nt)
#pragma unroll
    for (int rr = 0; rr < 4; ++rr)
      pw[(q4 * 4 + rr) * PS + nt * 16 + r16] = f2bf(lg[nt][rr]);

  // O = P(16x96) @ Vcat(96x64), img part pre-scaled
  f32x4 oc[4];
#pragma unroll
  for (int dt = 0; dt < 4; ++dt) {
    oc[dt] = zero;
#pragma unroll
    for (int kc = 0; kc < 3; ++kc) {
      bf16x8 pf = *(const bf16x8*)(pw + r16 * PS + kc * 32 + q4 * 8);
      bf16x8 vf = *(const bf16x8*)(Vt + (dt * 16 + r16) * PS + kc * 32 + q4 * 8);
      oc[dt] = __builtin_amdgcn_mfma_f32_16x16x32_bf16(pf, vf, oc[dt], 0, 0, 0);
    }
  }

  // store (b, s, h*64+d) bf16 for the output projection GEMM
#pragma unroll
  for (int dt = 0; dt < 4; ++dt)
#pragma unroll
    for (int rr = 0; rr < 4; ++rr) {
      int m = s0 + q4 * 4 + rr;
      int d = dt * 16 + r16;
      out[((size_t)b * 4096 + m) * 1280 + h * 64 + d] = f2bf(oc[dt][rr]);
    }
}

// ---------- launch ----------
extern "C" void kernel_launch(void* const* d_in, const int* in_sizes, int n_in,
                              void* d_out, int out_size, void* d_ws, size_t ws_size,
                              hipStream_t stream) {
  const float* x    = (const float*)d_in[0];
  const float* ctx  = (const float*)d_in[1];
  const float* scal = (const float*)d_in[2];
  // d_in[3] = num_img_token (fixed 16; eos = 77)
  const float* Wq   = (const float*)d_in[4];
  const float* Wk   = (const float*)d_in[5];
  const float* Wv   = (const float*)d_in[6];
  const float* Wkip = (const float*)d_in[7];
  const float* Wvip = (const float*)d_in[8];
  const float* Wout = (const float*)d_in[9];
  const float* bout = (const float*)d_in[10];
  float* out = (float*)d_out;

  char* ws = (char*)d_ws;
  size_t off = 0;
  auto alloc = [&](size_t elems) -> short* {
    short* p = (short*)(ws + off);
    off += (elems * 2 + 255) & ~(size_t)255;
    return p;
  };
  short* xb    = alloc(32768UL * 1280);   // also reused as attn output (x dead after Q proj)
  short* txtb  = alloc(616UL * 2048);
  short* imgb  = alloc(128UL * 2048);
  short* Wqb   = alloc(1280UL * 1280);
  short* Wkb   = alloc(1280UL * 2048);
  short* Wvb   = alloc(1280UL * 2048);
  short* Wkipb = alloc(1280UL * 2048);
  short* Wvipb = alloc(1280UL * 2048);
  short* Woutb = alloc(1280UL * 1280);
  short* qb    = alloc(32768UL * 1280);   // (b,h,4096,64)
  short* kb    = alloc(160UL * 77 * 64);
  short* vb    = alloc(160UL * 77 * 64);
  short* kib   = alloc(160UL * 16 * 64);
  short* vib   = alloc(160UL * 16 * 64);
  short* attnb = xb;

  auto cvt = [&](const float* s, short* d, long n) {
    int blocks = (int)((n / 4 + 255) / 256);
    k_cvt<<<blocks, 256, 0, stream>>>(s, d, (int)n);
  };
  cvt(x, xb, 32768L * 1280);
  cvt(Wq, Wqb, 1280L * 1280);
  cvt(Wk, Wkb, 1280L * 2048);
  cvt(Wv, Wvb, 1280L * 2048);
  cvt(Wkip, Wkipb, 1280L * 2048);
  cvt(Wvip, Wvipb, 1280L * 2048);
  cvt(Wout, Woutb, 1280L * 1280);
  {
    long n1 = 8L * 77 * 2048;
    k_cvt_ctx<<<(int)((n1 / 4 + 255) / 256), 256, 0, stream>>>(ctx, txtb, 77, 0);
    long n2 = 8L * 16 * 2048;
    k_cvt_ctx<<<(int)((n2 / 4 + 255) / 256), 256, 0, stream>>>(ctx, imgb, 16, 77);
  }

  { dim3 g(10, 256); k_gemm<0><<<g, 256, 0, stream>>>(xb, Wqb, qb, nullptr, 32768, 1280, 1280, 4096); }
  { dim3 g(10, 5);
    k_gemm<0><<<g, 256, 0, stream>>>(txtb, Wkb, kb, nullptr, 616, 1280, 2048, 77);
    k_gemm<0><<<g, 256, 0, stream>>>(txtb, Wvb, vb, nullptr, 616, 1280, 2048, 77); }
  { dim3 g(10, 1);
    k_gemm<0><<<g, 256, 0, stream>>>(imgb, Wkipb, kib, nullptr, 128, 1280, 2048, 16);
    k_gemm<0><<<g, 256, 0, stream>>>(imgb, Wvipb, vib, nullptr, 128, 1280, 2048, 16); }
  { dim3 g(64, 20, 8);
    k_attn<<<g, 256, 0, stream>>>(qb, kb, vb, kib, vib, scal, attnb); }
  { dim3 g(10, 256);
    k_gemm<1><<<g, 256, 0, stream>>>(attnb, Woutb, out, bout, 32768, 1280, 1280, 1); }
}

// Round 2
// 882.783 us; speedup vs baseline: 1.1063x; 1.1063x over previous
//
#include <hip/hip_runtime.h>
#include <stdint.h>
#include <stddef.h>

// ---------- types ----------
typedef __attribute__((ext_vector_type(8))) short bf16x8;  // 8 bf16 (4 VGPRs)
typedef __attribute__((ext_vector_type(4))) short bf16x4;
typedef __attribute__((ext_vector_type(4))) float f32x4;

typedef const __attribute__((address_space(1))) uint32_t gas_u32;
typedef __attribute__((address_space(3))) uint32_t las_u32;

__device__ __forceinline__ short f2bf(float f) {
  union { float f; uint32_t u; } c; c.f = f;
  uint32_t u = c.u;
  u += 0x7fffu + ((u >> 16) & 1u);   // RNE
  return (short)(u >> 16);
}

// ---------- fp32 -> bf16 convert ----------
__global__ void k_cvt(const float* __restrict__ src, short* __restrict__ dst, int n) {
  int i = (blockIdx.x * 256 + threadIdx.x) * 4;
  if (i + 4 <= n) {
    float4 v = *(const float4*)(src + i);
    bf16x4 o = { f2bf(v.x), f2bf(v.y), f2bf(v.z), f2bf(v.w) };
    *(bf16x4*)(dst + i) = o;
  } else {
    for (; i < n; ++i) dst[i] = f2bf(src[i]);
  }
}

// gather rows [row0, row0+rpb) of each batch's (93,2048) context into packed (8*rpb,2048) bf16
__global__ void k_cvt_ctx(const float* __restrict__ ctx, short* __restrict__ dst,
                          int rpb, int row0) {
  long total = 8L * rpb * 2048;
  long i = ((long)blockIdx.x * 256 + threadIdx.x) * 4;
  if (i >= total) return;
  int c = (int)(i & 2047);
  long rs = i >> 11;
  int b = (int)(rs / rpb);
  int s = (int)(rs - (long)b * rpb);
  const float* sp = ctx + ((long)(b * 93 + row0 + s) * 2048 + c);
  float4 v = *(const float4*)sp;
  bf16x4 o = { f2bf(v.x), f2bf(v.y), f2bf(v.z), f2bf(v.w) };
  *(bf16x4*)(dst + i) = o;
}

// ---------- GEMM: C[M,N] = A[M,K] * B[N,K]^T  (both row-major, bf16, fp32 acc) ----------
// LDS layout is XOR-swizzled: within each 64B row (4x 16B chunks), global chunk c
// of row r is stored at slot c ^ ((r>>1)&3). This spreads the 16-row fragment-read
// column across all 8 bank-groups (max 2-way aliasing = free, m136) instead of the
// unswizzled 8-way conflict (bank-group = (r*4)%8 ∈ {0,4} only).
// MODE 0: store bf16 head-permuted: grp = h/20 selects K vs V half (grp always 0 for Q):
//         out[((grp*160 + b*20 + h%20)*SPB + s)*64 + d],  h=n>>6, d=n&63
// MODE 1: store fp32 row-major + bias[n]
template <int MODE>
__global__ __launch_bounds__(256)
void k_gemm(const short* __restrict__ A, const short* __restrict__ Bm,
            void* __restrict__ out, const float* __restrict__ bias,
            int Mreal, int N, int K, int SPB) {
  __shared__ __align__(16) short As[128 * 32];
  __shared__ __align__(16) short Bs[128 * 32];
  const int t = threadIdx.x;
  const int lane = t & 63, wave = t >> 6;
  const int wm = (wave >> 1) * 64, wn = (wave & 1) * 64;
  const int m0 = blockIdx.y * 128, n0 = blockIdx.x * 128;
  const int q4 = lane >> 4, r16 = lane & 15;

  f32x4 zero = {0.f, 0.f, 0.f, 0.f};
  f32x4 acc[4][4];
#pragma unroll
  for (int i = 0; i < 4; ++i)
#pragma unroll
    for (int j = 0; j < 4; ++j) acc[i][j] = zero;

  // staging: 512 16B chunks per tile over 256 threads (2 each). LDS dest is
  // lane-contiguous (global_load_lds constraint); global source chunk is
  // swizzle-permuted so readers see slot = c ^ ((r>>1)&3).
  const int p0 = t, p1 = t + 256;
  const int ar0 = p0 >> 2, ac0 = (((p0 & 3) ^ ((ar0 >> 1) & 3))) * 8;
  const int ar1 = p1 >> 2, ac1 = (((p1 & 3) ^ ((ar1 >> 1) & 3))) * 8;
  int gm0 = m0 + ar0; if (gm0 >= Mreal) gm0 = Mreal - 1;
  int gm1 = m0 + ar1; if (gm1 >= Mreal) gm1 = Mreal - 1;
  const short* ga0 = A + (size_t)gm0 * K + ac0;
  const short* ga1 = A + (size_t)gm1 * K + ac1;
  const short* gb0 = Bm + (size_t)(n0 + ar0) * K + ac0;
  const short* gb1 = Bm + (size_t)(n0 + ar1) * K + ac1;

  // reader swizzle: slot for chunk q4 of row (…+r16); wave-uniform per lane,
  // loop-invariant (row base is a multiple of 16, so (row>>1)&3 == (r16>>1)&3)
  const int swz = (q4 ^ ((r16 >> 1) & 3)) * 8;

  for (int k0 = 0; k0 < K; k0 += 32) {
    __builtin_amdgcn_global_load_lds((gas_u32*)(ga0 + k0), (las_u32*)(As + p0 * 8), 16, 0, 0);
    __builtin_amdgcn_global_load_lds((gas_u32*)(ga1 + k0), (las_u32*)(As + p1 * 8), 16, 0, 0);
    __builtin_amdgcn_global_load_lds((gas_u32*)(gb0 + k0), (las_u32*)(Bs + p0 * 8), 16, 0, 0);
    __builtin_amdgcn_global_load_lds((gas_u32*)(gb1 + k0), (las_u32*)(Bs + p1 * 8), 16, 0, 0);
    __syncthreads();

    bf16x8 af[4], bf[4];
#pragma unroll
    for (int i = 0; i < 4; ++i)
      af[i] = *(const bf16x8*)(As + (wm + i * 16 + r16) * 32 + swz);
#pragma unroll
    for (int j = 0; j < 4; ++j)
      bf[j] = *(const bf16x8*)(Bs + (wn + j * 16 + r16) * 32 + swz);
#pragma unroll
    for (int i = 0; i < 4; ++i)
#pragma unroll
      for (int j = 0; j < 4; ++j)
        acc[i][j] = __builtin_amdgcn_mfma_f32_16x16x32_bf16(af[i], bf[j], acc[i][j], 0, 0, 0);
    __syncthreads();
  }

  // D layout (verified): row = q4*4 + reg, col = r16 within each 16x16 tile
  if (MODE == 0) {
    short* O = (short*)out;
#pragma unroll
    for (int i = 0; i < 4; ++i) {
#pragma unroll
      for (int rr = 0; rr < 4; ++rr) {
        int m = m0 + wm + i * 16 + q4 * 4 + rr;
        if (m < Mreal) {
          int bb, ss;
          if (SPB == 4096) { bb = m >> 12; ss = m & 4095; }
          else             { bb = m / SPB; ss = m - bb * SPB; }
#pragma unroll
          for (int j = 0; j < 4; ++j) {
            int n = n0 + wn + j * 16 + r16;
            int h = n >> 6, d = n & 63;
            int grp = (h >= 20) ? 1 : 0;        // K vs V half when N==2560
            int hl = h - grp * 20;
            O[(((size_t)(grp * 160 + bb * 20 + hl)) * SPB + ss) * 64 + d] = f2bf(acc[i][j][rr]);
          }
        }
      }
    }
  } else {
    float* O = (float*)out;
#pragma unroll
    for (int i = 0; i < 4; ++i) {
#pragma unroll
      for (int rr = 0; rr < 4; ++rr) {
        int m = m0 + wm + i * 16 + q4 * 4 + rr;
        if (m < Mreal) {
#pragma unroll
          for (int j = 0; j < 4; ++j) {
            int n = n0 + wn + j * 16 + r16;
            O[(size_t)m * N + n] = acc[i][j][rr] + bias[n];
          }
        }
      }
    }
  }
}

// ---------- fused dual attention: out = softmax(QKt^T/8)Vt + scale*softmax(QKi^T/8)Vi ----------
// Q,K,V in (b,h,s,64) bf16. Keys padded: rows 0..76 txt, 77..79 zero (masked), 80..95 img.
__global__ __launch_bounds__(256)
void k_attn(const short* __restrict__ qb, const short* __restrict__ kb,
            const short* __restrict__ vb, const short* __restrict__ kib,
            const short* __restrict__ vib, const float* __restrict__ scale_p,
            short* __restrict__ out) {
  constexpr int KS = 72;    // Ks row stride (shorts): 144B -> 2-way bank alias (free)
  constexpr int PS = 104;   // Vt/P row stride: 208B -> 2-way alias (free), 16B aligned
  __shared__ __align__(16) short Ks[96 * KS];
  __shared__ __align__(16) short Vt[64 * PS];      // transposed: Vt[d][key]
  __shared__ __align__(16) short Pp[4][16 * PS];   // per-wave P (A-layout staging)
  const int t = threadIdx.x, lane = t & 63, wave = t >> 6;
  const int q4 = lane >> 4, r16 = lane & 15;
  const int b = blockIdx.z, h = blockIdx.y, qt = blockIdx.x;
  const int bh = b * 20 + h;
  const short* kt = kb + (size_t)bh * 77 * 64;
  const short* vt = vb + (size_t)bh * 77 * 64;
  const short* ki = kib + (size_t)bh * 16 * 64;
  const short* vi = vib + (size_t)bh * 16 * 64;

  // stage K rows (16B chunks)
  for (int c = t; c < 96 * 8; c += 256) {
    int row = c >> 3, o = (c & 7) * 8;
    uint4 val = {0u, 0u, 0u, 0u};
    if (row < 77)       val = *(const uint4*)(kt + row * 64 + o);
    else if (row >= 80) val = *(const uint4*)(ki + (row - 80) * 64 + o);
    *(uint4*)(Ks + row * KS + o) = val;
  }
  // stage V transposed
  for (int i = t; i < 96 * 64; i += 256) {
    int key = i >> 6, d = i & 63;
    short v = 0;
    if (key < 77)       v = vt[key * 64 + d];
    else if (key >= 80) v = vi[(key - 80) * 64 + d];
    Vt[d * PS + key] = v;
  }
  __syncthreads();

  // per-wave: 16 q rows
  const int s0 = qt * 64 + wave * 16;
  const short* qp = qb + ((size_t)bh * 4096 + s0) * 64;
  bf16x8 qf[2];
#pragma unroll
  for (int kc = 0; kc < 2; ++kc)
    qf[kc] = *(const bf16x8*)(qp + r16 * 64 + kc * 32 + q4 * 8);

  f32x4 zero = {0.f, 0.f, 0.f, 0.f};
  f32x4 lg[6];  // logits tiles: 0..4 txt(80 padded), 5 img(16)
#pragma unroll
  for (int nt = 0; nt < 6; ++nt) {
    lg[nt] = zero;
#pragma unroll
    for (int kc = 0; kc < 2; ++kc) {
      bf16x8 kf = *(const bf16x8*)(Ks + (nt * 16 + r16) * KS + kc * 32 + q4 * 8);
      lg[nt] = __builtin_amdgcn_mfma_f32_16x16x32_bf16(qf[kc], kf, lg[nt], 0, 0, 0);
    }
  }

  const float sm = 0.125f;  // 1/sqrt(64)
  const float scl = scale_p[0];
#pragma unroll
  for (int nt = 0; nt < 6; ++nt)
#pragma unroll
    for (int rr = 0; rr < 4; ++rr) lg[nt][rr] *= sm;
  if (r16 >= 13) {  // txt tile 4: keys 64+r16 >= 77 are padding
#pragma unroll
    for (int rr = 0; rr < 4; ++rr) lg[4][rr] = -1e30f;
  }

  // two independent softmaxes; row rr lives in the 16 lanes of this quad at reg rr
#pragma unroll
  for (int rr = 0; rr < 4; ++rr) {
    float mx = -1e30f;
#pragma unroll
    for (int nt = 0; nt < 5; ++nt) mx = fmaxf(mx, lg[nt][rr]);
#pragma unroll
    for (int o = 1; o < 16; o <<= 1) mx = fmaxf(mx, __shfl_xor(mx, o, 64));
    float s = 0.f;
#pragma unroll
    for (int nt = 0; nt < 5; ++nt) {
      float p = __expf(lg[nt][rr] - mx);
      lg[nt][rr] = p; s += p;
    }
#pragma unroll
    for (int o = 1; o < 16; o <<= 1) s += __shfl_xor(s, o, 64);
    float inv = 1.f / s;
#pragma unroll
    for (int nt = 0; nt < 5; ++nt) lg[nt][rr] *= inv;

    float mi = lg[5][rr];
#pragma unroll
    for (int o = 1; o < 16; o <<= 1) mi = fmaxf(mi, __shfl_xor(mi, o, 64));
    float pi = __expf(lg[5][rr] - mi);
    float si = pi;
#pragma unroll
    for (int o = 1; o < 16; o <<= 1) si += __shfl_xor(si, o, 64);
    lg[5][rr] = pi * (scl / si);   // fold 'scale' into img probs
  }

  // C-layout -> A-layout via LDS round trip (wave-private, no barrier needed)
  short* pw = &Pp[wave][0];
#pragma unroll
  for (int nt = 0; nt < 6; ++nt)
#pragma unroll
    for (int rr = 0; rr < 4; ++rr)
      pw[(q4 * 4 + rr) * PS + nt * 16 + r16] = f2bf(lg[nt][rr]);

  // O = P(16x96) @ Vcat(96x64), img part pre-scaled
  f32x4 oc[4];
#pragma unroll
  for (int dt = 0; dt < 4; ++dt) {
    oc[dt] = zero;
#pragma unroll
    for (int kc = 0; kc < 3; ++kc) {
      bf16x8 pf = *(const bf16x8*)(pw + r16 * PS + kc * 32 + q4 * 8);
      bf16x8 vf = *(const bf16x8*)(Vt + (dt * 16 + r16) * PS + kc * 32 + q4 * 8);
      oc[dt] = __builtin_amdgcn_mfma_f32_16x16x32_bf16(pf, vf, oc[dt], 0, 0, 0);
    }
  }

  // store (b, s, h*64+d) bf16 for the output projection GEMM
#pragma unroll
  for (int dt = 0; dt < 4; ++dt)
#pragma unroll
    for (int rr = 0; rr < 4; ++rr) {
      int m = s0 + q4 * 4 + rr;
      int d = dt * 16 + r16;
      out[((size_t)b * 4096 + m) * 1280 + h * 64 + d] = f2bf(oc[dt][rr]);
    }
}

// ---------- launch ----------
extern "C" void kernel_launch(void* const* d_in, const int* in_sizes, int n_in,
                              void* d_out, int out_size, void* d_ws, size_t ws_size,
                              hipStream_t stream) {
  const float* x    = (const float*)d_in[0];
  const float* ctx  = (const float*)d_in[1];
  const float* scal = (const float*)d_in[2];
  // d_in[3] = num_img_token (fixed 16; eos = 77)
  const float* Wq   = (const float*)d_in[4];
  const float* Wk   = (const float*)d_in[5];
  const float* Wv   = (const float*)d_in[6];
  const float* Wkip = (const float*)d_in[7];
  const float* Wvip = (const float*)d_in[8];
  const float* Wout = (const float*)d_in[9];
  const float* bout = (const float*)d_in[10];
  float* out = (float*)d_out;

  char* ws = (char*)d_ws;
  size_t off = 0;
  auto alloc = [&](size_t elems) -> short* {
    short* p = (short*)(ws + off);
    off += (elems * 2 + 255) & ~(size_t)255;
    return p;
  };
  short* xb    = alloc(32768UL * 1280);   // also reused as attn output (x dead after Q proj)
  short* txtb  = alloc(616UL * 2048);
  short* imgb  = alloc(128UL * 2048);
  short* Wqb   = alloc(1280UL * 1280);
  // Wk|Wv contiguous (N=2560 merged KV projection); likewise Wkip|Wvip.
  // Each is 1280*2048*2 bytes = multiple of 256, so alloc() keeps them adjacent.
  short* Wkvb  = alloc(2UL * 1280 * 2048);
  short* Wkvip = alloc(2UL * 1280 * 2048);
  short* Woutb = alloc(1280UL * 1280);
  short* qb    = alloc(32768UL * 1280);   // (b,h,4096,64)
  short* kb    = alloc(2UL * 160 * 77 * 64);   // kb | vb adjacent (grp*160 indexing)
  short* kib   = alloc(2UL * 160 * 16 * 64);   // kib | vib adjacent
  short* vb    = kb  + 160UL * 77 * 64;
  short* vib   = kib + 160UL * 16 * 64;
  short* attnb = xb;

  auto cvt = [&](const float* s, short* d, long n) {
    int blocks = (int)((n / 4 + 255) / 256);
    k_cvt<<<blocks, 256, 0, stream>>>(s, d, (int)n);
  };
  cvt(x, xb, 32768L * 1280);
  cvt(Wq, Wqb, 1280L * 1280);
  cvt(Wk,   Wkvb,                 1280L * 2048);
  cvt(Wv,   Wkvb + 1280L * 2048,  1280L * 2048);
  cvt(Wkip, Wkvip,                1280L * 2048);
  cvt(Wvip, Wkvip + 1280L * 2048, 1280L * 2048);
  cvt(Wout, Woutb, 1280L * 1280);
  {
    long n1 = 8L * 77 * 2048;
    k_cvt_ctx<<<(int)((n1 / 4 + 255) / 256), 256, 0, stream>>>(ctx, txtb, 77, 0);
    long n2 = 8L * 16 * 2048;
    k_cvt_ctx<<<(int)((n2 / 4 + 255) / 256), 256, 0, stream>>>(ctx, imgb, 16, 77);
  }

  { dim3 g(10, 256); k_gemm<0><<<g, 256, 0, stream>>>(xb, Wqb, qb, nullptr, 32768, 1280, 1280, 4096); }
  { dim3 g(20, 5);
    k_gemm<0><<<g, 256, 0, stream>>>(txtb, Wkvb, kb, nullptr, 616, 2560, 2048, 77); }
  { dim3 g(20, 1);
    k_gemm<0><<<g, 256, 0, stream>>>(imgb, Wkvip, kib, nullptr, 128, 2560, 2048, 16); }
  { dim3 g(64, 20, 8);
    k_attn<<<g, 256, 0, stream>>>(qb, kb, vb, kib, vib, scal, attnb); }
  { dim3 g(10, 256);
    k_gemm<1><<<g, 256, 0, stream>>>(attnb, Woutb, out, bout, 32768, 1280, 1280, 1); }
}